// Round 4
// baseline (136.207 us; speedup 1.0000x reference)
//
#include <hip/hip_runtime.h>
#include <math.h>

#define NBINS   8192
#define L_AUDIO 16777216
#define T_FRAMES 2049
#define NQ      8400
#define MUNK    8188

__device__ __forceinline__ int refl_idx(int m) {
    if (m < 0) m = -m;
    if (m >= L_AUDIO) m = 2 * L_AUDIO - 2 - m;
    return m;
}
__device__ __forceinline__ float2 cmul(float2 a, float2 b) {
    return make_float2(fmaf(a.x, b.x, -a.y * b.y), fmaf(a.x, b.y, a.y * b.x));
}
__device__ __forceinline__ float2 csq(float2 a) {
    return make_float2(fmaf(a.x, a.x, -a.y * a.y), 2.0f * a.x * a.y);
}
// Gentleman-Sande radix-4: w_r = W_L^{r*q0}; output r stays at q0 + r*L/4.
__device__ __forceinline__ void r4(float2& x0, float2& x1, float2& x2, float2& x3,
                                   float2 w1, float2 w2, float2 w3) {
    float2 t0 = make_float2(x0.x + x2.x, x0.y + x2.y);
    float2 t1 = make_float2(x1.x + x3.x, x1.y + x3.y);
    float2 t2 = make_float2(x0.x - x2.x, x0.y - x2.y);
    float2 t3 = make_float2(x1.x - x3.x, x1.y - x3.y);
    float2 b1 = make_float2(t2.x + t3.y, t2.y - t3.x);   // t2 - i*t3
    float2 b3 = make_float2(t2.x - t3.y, t2.y + t3.x);   // t2 + i*t3
    x0 = make_float2(t0.x + t1.x, t0.y + t1.y);
    x1 = cmul(w1, b1);
    x2 = cmul(w2, make_float2(t0.x - t1.x, t0.y - t1.y));
    x3 = cmul(w3, b3);
}
// radix-8 on 8 elems at q0 + j*L/8; all twiddles derived from w = W_L^{q0}.
__device__ __forceinline__ void r8(float2 x[8], float2 w) {
    const float c = 0.70710678118654752f;
    float2 w2 = csq(w), w3 = cmul(w, w2), w4 = csq(w2);
    r4(x[0], x[2], x[4], x[6], w, w2, w3);
    float2 wE   = make_float2(c * (w.x + w.y),  c * (w.y - w.x));     // w*e^{-i pi/4}
    float2 w2E2 = make_float2(w2.y, -w2.x);                           // w2*(-i)
    float2 w3E3 = make_float2(c * (w3.y - w3.x), -c * (w3.x + w3.y)); // w3*e^{-i3pi/4}
    r4(x[1], x[3], x[5], x[7], wE, w2E2, w3E3);
#pragma unroll
    for (int r = 0; r < 4; ++r) {
        float2 a = x[2 * r], b = x[2 * r + 1];
        x[2 * r]     = make_float2(a.x + b.x, a.y + b.y);
        float2 d     = make_float2(a.x - b.x, a.y - b.y);
        x[2 * r + 1] = cmul(w4, d);
    }
}

// ---------------- Kernel A: 512 threads, in-place 8192-pt complex FFT as
// 3x radix-8 + fused (radix-8 x2 + radix-2 in regs); window+pack fused into
// pass 1 via per-thread base x compile-time rotation. unroll(1) groups.
// Round-4: body identical to the verified 123.7us round-0 kernel (rounds
// 1-2: any extra live float2s spill at the 128-VGPR budget; round 3:
// anti-phase stagger = pure loss, blocks don't convoy). Only addition:
// block 0 zeroes the fused-post kernel's barrier counters (spec[8188:90]).
__global__ __launch_bounds__(512, 2) void fft_pow_kernel(
        const float* __restrict__ audio, float* __restrict__ partial, int P) {
    __shared__ float2 buf[8718];   // phi(p) = p + (p>>4) + (p>>9), max 8717
    const int t = threadIdx.x;

    if (blockIdx.x == 0 && t == 0) {   // counters live at spec[8188..8189]
        unsigned int* cz = (unsigned int*)(partial - 4);
        cz[0] = 0u; cz[1] = 0u;
    }

    const int phit  = t + (t >> 4);                         // phi(t), t < 512
    const int q2    = t & 127;
    const int base2 = 1090 * (t >> 7) + q2 + (q2 >> 4);     // pass2 base
    const int base3 = 136 * (t >> 4) + ((t >> 4) >> 2) + (t & 15);
    const int base4 = 17 * t + (t >> 5);
    const int tp    = (512 - t) & 511;
    // output position of bin k = t + 512u: PB(t) + off(u) for the
    // radix-[8,8,8,8,2] chain (verified absmax 0 since round 5)
    const int PBt = (t & 3) * 2048 + ((t >> 2) & 1) * 1024 + ((t >> 3) & 3) * 256
                  + ((t >> 5) & 1) * 128 + ((t >> 6) & 3) * 32 + ((t >> 8) & 1) * 16;
    const int PBp = (tp & 3) * 2048 + ((tp >> 2) & 1) * 1024 + ((tp >> 3) & 3) * 256
                  + ((tp >> 5) & 1) * 128 + ((tp >> 6) & 3) * 32 + ((tp >> 8) & 1) * 16;
    const int ubA = PBt + (PBt >> 4) + (PBt >> 9);
    const int ubB = PBp + (PBp >> 4) + (PBp >> 9);

    const float2 ONE = make_float2(1.0f, 0.0f);
    const float2 K8  = make_float2(0.92387953251128674f, -0.38268343236508977f); // e^{-i pi/8}
    const float2 KD  = make_float2(0.99999992646574f, -0.00038349518757f);       // e^{-i pi/8192}
    float2 wU  = make_float2(cospif((float)t * (1.0f / 8192.0f)),
                             -sinpif((float)t * (1.0f / 8192.0f)));  // W_16384^t
    float2 w1  = csq(wU);                                            // W_8192^t
    float2 wodd = cmul(w1, KD);                                      // e^{-i pi(2t+1)/8192}
    float2 w2t = make_float2(cospif((float)q2 * (1.0f / 512.0f)),
                             -sinpif((float)q2 * (1.0f / 512.0f)));  // W_1024^(t&127)
    float2 w3t = make_float2(cospif((float)(t & 15) * (1.0f / 64.0f)),
                             -sinpif((float)(t & 15) * (1.0f / 64.0f))); // W_128^(t&15)
    // untangle twiddle step: W_16384^{512u} = e^{-i pi u/16}, compile-time
    const float K16c[16] = {1.0f, 0.98078528040323044f, 0.92387953251128674f,
        0.83146961230254524f, 0.70710678118654752f, 0.55557023301960222f,
        0.38268343236508977f, 0.19509032201612825f, 0.0f, -0.19509032201612825f,
        -0.38268343236508977f, -0.55557023301960222f, -0.70710678118654752f,
        -0.83146961230254524f, -0.92387953251128674f, -0.98078528040323044f};
    const float K16s[16] = {0.0f, -0.19509032201612825f, -0.38268343236508977f,
        -0.55557023301960222f, -0.70710678118654752f, -0.83146961230254524f,
        -0.92387953251128674f, -0.98078528040323044f, -1.0f, -0.98078528040323044f,
        -0.92387953251128674f, -0.83146961230254524f, -0.70710678118654752f,
        -0.55557023301960222f, -0.38268343236508977f, -0.19509032201612825f};
    // window rotation: cos/sin(pi u/8), u = g + 2j in [0,16)
    const float W16C[16] = {1.0f, 0.92387953251128674f, 0.70710678118654752f,
        0.38268343236508977f, 0.0f, -0.38268343236508977f, -0.70710678118654752f,
        -0.92387953251128674f, -1.0f, -0.92387953251128674f, -0.70710678118654752f,
        -0.38268343236508977f, 0.0f, 0.38268343236508977f, 0.70710678118654752f,
        0.92387953251128674f};
    const float W16S[16] = {0.0f, 0.38268343236508977f, 0.70710678118654752f,
        0.92387953251128674f, 1.0f, 0.92387953251128674f, 0.70710678118654752f,
        0.38268343236508977f, 0.0f, -0.38268343236508977f, -0.70710678118654752f,
        -0.92387953251128674f, -1.0f, -0.92387953251128674f, -0.70710678118654752f,
        -0.38268343236508977f};

    float acc[16];
#pragma unroll
    for (int u = 0; u < 16; ++u) acc[u] = 0.0f;

    for (int f = blockIdx.x; f < T_FRAMES; f += P) {
        __syncthreads();   // previous frame's untangle reads vs pass-1 writes
        // ---- pass 1 (fused window+pack): L=8192, q0 = t + 512g ----
        const bool interior = (f != 0) && (f != T_FRAMES - 1);
        const float2* au2 = (const float2*)audio + 4096 * (f - 1);
        const int baseS = f * 8192 - 8192;
#pragma unroll 1
        for (int g = 0; g < 2; ++g) {
            float2 x[8];
            if (interior) {
#pragma unroll
                for (int j = 0; j < 8; ++j) {
                    int idx = t + 512 * g + 1024 * j;
                    float2 p = au2[idx];
                    const int uix = g + 2 * j;
                    float c0 = 0.5f - 0.5f * (w1.x * W16C[uix] + w1.y * W16S[uix]);
                    float c1 = 0.5f - 0.5f * (wodd.x * W16C[uix] + wodd.y * W16S[uix]);
                    x[j] = make_float2(p.x * c0, p.y * c1);
                }
            } else {
#pragma unroll
                for (int j = 0; j < 8; ++j) {
                    int idx = t + 512 * g + 1024 * j;
                    float a0 = audio[refl_idx(baseS + 2 * idx)];
                    float a1 = audio[refl_idx(baseS + 2 * idx + 1)];
                    const int uix = g + 2 * j;
                    float c0 = 0.5f - 0.5f * (w1.x * W16C[uix] + w1.y * W16S[uix]);
                    float c1 = 0.5f - 0.5f * (wodd.x * W16C[uix] + wodd.y * W16S[uix]);
                    x[j] = make_float2(a0 * c0, a1 * c1);
                }
            }
            float2 w = g ? cmul(w1, K8) : w1;
            r8(x, w);
#pragma unroll
            for (int j = 0; j < 8; ++j) buf[phit + 545 * g + 1090 * j] = x[j];
        }
        __syncthreads();
        // pass 2: L=1024, B = (t>>7)+4g, q0 = t&127, stride 128
#pragma unroll 1
        for (int g = 0; g < 2; ++g) {
            float2 x[8];
            const int bs = base2 + 4360 * g;
#pragma unroll
            for (int j = 0; j < 8; ++j) x[j] = buf[bs + 136 * j + (j >> 2)];
            r8(x, w2t);
#pragma unroll
            for (int j = 0; j < 8; ++j) buf[bs + 136 * j + (j >> 2)] = x[j];
        }
        __syncthreads();
        // pass 3: L=128, B = (t>>4)+32g, q0 = t&15, stride 16
#pragma unroll 1
        for (int g = 0; g < 2; ++g) {
            float2 x[8];
            const int bs = base3 + 4360 * g;
#pragma unroll
            for (int j = 0; j < 8; ++j) x[j] = buf[bs + 17 * j];
            r8(x, w3t);
#pragma unroll
            for (int j = 0; j < 8; ++j) buf[bs + 17 * j] = x[j];
        }
        __syncthreads();
        // pass 4+5 fused: thread t owns logical [16t,16t+16); radix-8 on both
        // parity groups in registers; radix-2 pairs are (a[j], x[j]).
        {
            float2 a[8], x[8];
#pragma unroll
            for (int j = 0; j < 8; ++j) a[j] = buf[base4 + 2 * j];
            r8(a, ONE);
#pragma unroll
            for (int j = 0; j < 8; ++j) x[j] = buf[base4 + 1 + 2 * j];
            r8(x, K8);
#pragma unroll
            for (int j = 0; j < 8; ++j) {
                buf[base4 + 2 * j]     = make_float2(a[j].x + x[j].x, a[j].y + x[j].y);
                buf[base4 + 2 * j + 1] = make_float2(a[j].x - x[j].x, a[j].y - x[j].y);
            }
        }
        __syncthreads();
        // untangle real FFT at digit-reversed positions, power, log
#pragma unroll
        for (int u = 0; u < 16; ++u) {
            const int off = (u & 3) * 4 + ((u >> 2) & 1) * 2 + (u >> 3);
            int u2 = t ? (15 - u) : ((16 - u) & 15);
            int off2 = (u2 & 3) * 4 + ((u2 >> 2) & 1) * 2 + (u2 >> 3);
            float2 A = buf[ubA + off];
            float2 B = buf[ubB + off2];
            float Xer = 0.5f * (A.x + B.x);
            float Xei = 0.5f * (A.y - B.y);
            float Xor = 0.5f * (A.y + B.y);
            float Xoi = -0.5f * (A.x - B.x);
            float2 w = cmul(wU, make_float2(K16c[u], K16s[u]));  // W_16384^{t+512u}
            float Xr = Xer + Xor * w.x - Xoi * w.y;
            float Xi = Xei + Xor * w.y + Xoi * w.x;
            float pw = Xr * Xr + Xi * Xi;
            acc[u] += __logf(fmaf(100.0f, pw, 1.0f));
        }
    }
#pragma unroll
    for (int u = 0; u < 16; ++u)
        partial[(size_t)blockIdx.x * NBINS + t + 512 * u] = acc[u];
}

// ---------------- Fused post kernel: reduce + spline + comb in ONE launch ---
// 128 blocks x 256 threads (all resident: 128 < 256 CUs -> spin-safe).
// Phase 1: deterministic reduce (identical math to old reduce_kernel; skips
//   writing spec[8188..8191], never read downstream — counters live there).
// Barrier A: agent-scope release fetch_add / acquire spin (per-XCD L2s are
//   not coherent; acquire/release atomics emit the needed cache ops).
// Phase 2: blocks 0..32 run the old cent_spline_kernel body.
// Barrier B: last-arriving block runs the old comb_argmax body (result is
//   executor-independent -> deterministic).
__global__ __launch_bounds__(256) void fused_post_kernel(
        float* __restrict__ ws, const float* __restrict__ wsm,
        const float* __restrict__ wdet, float* __restrict__ out, int P) {
    float* spec    = ws;
    float* partial = ws + NBINS;
    float* filt    = ws + 2 * NBINS;    // overlaps partial rows (dead after ph.1)
    unsigned int* c0 = (unsigned int*)(ws + 8188);
    unsigned int* c1 = (unsigned int*)(ws + 8189);
    const int tid = threadIdx.x;
    const int bid = blockIdx.x;

    // ---- phase 1: reduce partial (P rows) -> spec ----
    {
        __shared__ float sred[4][65];
        const int bin0 = bid * 64;
        const int bo = tid & 63;
        const int g  = tid >> 6;           // 0..3
        const int rows = P >> 2;
        float a0 = 0.f, a1 = 0.f;
        int r = 0;
        const float* base = partial + (size_t)g * rows * NBINS + bin0 + bo;
        for (; r + 2 <= rows; r += 2) {
            a0 += base[(size_t)r * NBINS];
            a1 += base[(size_t)(r + 1) * NBINS];
        }
        for (; r < rows; ++r) a0 += base[(size_t)r * NBINS];
        sred[g][bo] = a0 + a1;
        __syncthreads();
        if (tid < 64) {
            int bin = bin0 + tid;
            if (bin < 8188)
                spec[bin] = (sred[0][tid] + sred[1][tid])
                          + (sred[2][tid] + sred[3][tid]);
        }
        __syncthreads();
    }
    // ---- barrier A ----
    __threadfence();
    if (tid == 0)
        __hip_atomic_fetch_add(c0, 1u, __ATOMIC_RELEASE, __HIP_MEMORY_SCOPE_AGENT);
    if (bid >= 33) return;
    if (tid == 0) {
        while (__hip_atomic_load(c0, __ATOMIC_ACQUIRE, __HIP_MEMORY_SCOPE_AGENT) < 128u) {}
    }
    __syncthreads();
    __threadfence();

    // ---- phase 2: spline + smooth + relu (old cent_spline_kernel body) ----
    {
        __shared__ float ys[768];
        __shared__ float dps[704];
        __shared__ float Ms[640];
        __shared__ float cs[356];
        __shared__ float wsm_s[101];
        __shared__ float invden_s[64];
        const int j0 = bid * 256;
        const float h = 22050.0f / 16384.0f;
        const float hh = h * h;

        if (tid == 0) {
            double v = 0.25;
            invden_s[0] = 0.25f;
            for (int i = 1; i < 64; ++i) { v = 1.0 / (4.0 - v); invden_s[i] = (float)v; }
        }
        for (int r = tid; r < 101; r += 256) wsm_s[r] = wsm[r];

        const int jLo = max(j0 - 50, 0);
        const int jHi = min(j0 + 305, NQ - 1);
        const float xqLo = (float)(440.0 * exp2(((double)jLo * 0.01 - 45.0) * (1.0 / 12.0)));
        const float xqHi = (float)(440.0 * exp2(((double)jHi * 0.01 - 45.0) * (1.0 / 12.0)));
        const int iLo = min(max((int)floorf(xqLo / h), 0), 8190);
        const int iHi = min(max((int)floorf(xqHi / h), 0), 8190);
        const int pLo = max(iLo - 2, 0);
        const int pHi = min(iHi - 1, MUNK - 1);
        const int bHi = min(pHi + 64, MUNK - 1);
        const int yLo = max(pLo - 64, 0);
        const int yHi = bHi + 3;
        const int ny  = yHi - yLo + 1;

        for (int k = tid; k < ny; k += 256) ys[k] = spec[yLo + k];
        __syncthreads();
        const float cst = invden_s[63];   // 2 - sqrt(3)

        {
            const int nch = (bHi - pLo + 32) >> 5;
            if (tid < nch) {
                const int s = pLo + (tid << 5);
                const int e = min(s + 31, bHi);
                const int wstart = max(s - 64, 0);
                float dprev = 0.0f;
                for (int i = wstart; i <= e; ++i) {
                    float d1 = (ys[i + 1 - yLo] - 2.0f * ys[i + 2 - yLo]
                                + ys[i + 3 - yLo]) / hh;
                    float r = 6.0f * d1;
                    if (i == 0) r -= (ys[0] - 2.0f * ys[1] + ys[2]) / hh;
                    float val = (i == 0) ? r : (r - dprev);
                    float dpv = val * ((i < 64) ? invden_s[i] : cst);
                    if (i >= s) dps[i - pLo] = dpv;
                    dprev = dpv;
                }
            }
        }
        __syncthreads();
        {
            const int nch = (pHi - pLo + 32) >> 5;
            if (tid < nch) {
                const int s = pLo + (tid << 5);
                const int e = min(s + 31, pHi);
                const int ws2 = min(e + 64, bHi);
                float xnext = 0.0f;
                for (int i = ws2; i >= s; --i) {
                    float cp = (i == MUNK - 1) ? 0.0f : ((i < 64) ? invden_s[i] : cst);
                    float xv = dps[i - pLo] - cp * xnext;
                    if (i <= e) Ms[2 + i - iLo] = xv;
                    xnext = xv;
                }
            }
        }
        __syncthreads();
        for (int r = tid; r < 356; r += 256) {
            int j = j0 - 50 + r;
            float v = 0.0f;
            if (j >= 0 && j < NQ) {
                double e = ((double)j * 0.01 - 45.0) * (1.0 / 12.0);
                float xq = (float)(440.0 * exp2(e));
                int i = min(max((int)floorf(xq / h), 0), 8190);
                float tt = xq - (float)i * h;
                float uu = h - tt;
                float Mi = Ms[i - iLo], Mi1 = Ms[i + 1 - iLo];
                float yi = ys[i - yLo], yi1 = ys[i + 1 - yLo];
                v = (Mi * uu * uu * uu + Mi1 * tt * tt * tt) / (6.0f * h)
                  + (yi - Mi * hh / 6.0f) * uu / h
                  + (yi1 - Mi1 * hh / 6.0f) * tt / h;
            }
            cs[r] = v;
        }
        __syncthreads();
        int j = j0 + tid;
        if (j < NQ) {
            float s = 0.0f;
            for (int m = 0; m < 101; ++m) s = fmaf(wsm_s[m], cs[tid + 100 - m], s);
            float fv = cs[tid + 50] - s;
            filt[j] = fv > 0.0f ? fv : 0.0f;
        }
        __syncthreads();
    }
    // ---- barrier B: last of the 33 spline blocks runs the comb ----
    __shared__ unsigned int lastflag;
    __threadfence();
    if (tid == 0) {
        unsigned int prev =
            __hip_atomic_fetch_add(c1, 1u, __ATOMIC_ACQ_REL, __HIP_MEMORY_SCOPE_AGENT);
        lastflag = (prev == 32u) ? 1u : 0u;
    }
    __syncthreads();
    if (!lastflag) return;
    __threadfence();

    // ---- phase 3: dilated comb + argmax (old comb_argmax_kernel body) ----
    {
        __shared__ float fs[NQ];
        __shared__ float wd[84];
        __shared__ float sc[100];
        const int t = tid;
        for (int k = t; k < NQ; k += 256) fs[k] = filt[k];
        if (t < 84) wd[t] = wdet[t];
        __syncthreads();
        if (t < 100) {
            float s = 0.0f;
            for (int k = 0; k < 84; ++k) {
                int ix = t - 50 + 100 * k;
                if (ix >= 0) s = fmaf(wd[k], fs[ix], s);
            }
            sc[t] = s;
            out[1 + t] = s;
        }
        __syncthreads();
        if (t < 64) {    // wave argmax, first-max tie-break
            float v = (t < 100) ? sc[t] : -1e30f;
            int i = t;
            int t2 = t + 64;
            float v2 = (t2 < 100) ? sc[t2] : -1e30f;
            if (v2 > v) { v = v2; i = t2; }
#pragma unroll
            for (int off = 32; off; off >>= 1) {
                float ov = __shfl_xor(v, off, 64);
                int   oi = __shfl_xor(i, off, 64);
                if (ov > v || (ov == v && oi < i)) { v = ov; i = oi; }
            }
            if (t == 0) out[0] = (float)(i - 50);
        }
    }
}

extern "C" void kernel_launch(void* const* d_in, const int* in_sizes, int n_in,
                              void* d_out, int out_size, void* d_ws, size_t ws_size,
                              hipStream_t stream) {
    const float* audio = (const float*)d_in[0];
    const float* wsm   = (const float*)d_in[1];
    const float* wdet  = (const float*)d_in[2];
    float* out = (float*)d_out;
    float* ws  = (float*)d_ws;

    long cap = (long)(ws_size / sizeof(float) / NBINS) - 1;
    int P = (int)(cap < 4 ? 4 : (cap > 512 ? 512 : cap));
    P &= ~3;                               // multiple of 4 for the reduce
    float* partial = ws + NBINS;           // P rows of 8192

    hipLaunchKernelGGL(fft_pow_kernel, dim3(P), dim3(512), 0, stream,
                       audio, partial, P);
    hipLaunchKernelGGL(fused_post_kernel, dim3(128), dim3(256), 0, stream,
                       ws, wsm, wdet, out, P);
}

// Round 5
// 112.371 us; speedup vs baseline: 1.2121x; 1.2121x over previous
//
#include <hip/hip_runtime.h>
#include <math.h>

#define NBINS   8192
#define L_AUDIO 16777216
#define T_FRAMES 2049
#define NQ      8400
#define MUNK    8188

__device__ __forceinline__ int refl_idx(int m) {
    if (m < 0) m = -m;
    if (m >= L_AUDIO) m = 2 * L_AUDIO - 2 - m;
    return m;
}
__device__ __forceinline__ float2 cmul(float2 a, float2 b) {
    return make_float2(fmaf(a.x, b.x, -a.y * b.y), fmaf(a.x, b.y, a.y * b.x));
}
__device__ __forceinline__ float2 csq(float2 a) {
    return make_float2(fmaf(a.x, a.x, -a.y * a.y), 2.0f * a.x * a.y);
}
// Gentleman-Sande radix-4: w_r = W_L^{r*q0}; output r stays at q0 + r*L/4.
__device__ __forceinline__ void r4(float2& x0, float2& x1, float2& x2, float2& x3,
                                   float2 w1, float2 w2, float2 w3) {
    float2 t0 = make_float2(x0.x + x2.x, x0.y + x2.y);
    float2 t1 = make_float2(x1.x + x3.x, x1.y + x3.y);
    float2 t2 = make_float2(x0.x - x2.x, x0.y - x2.y);
    float2 t3 = make_float2(x1.x - x3.x, x1.y - x3.y);
    float2 b1 = make_float2(t2.x + t3.y, t2.y - t3.x);   // t2 - i*t3
    float2 b3 = make_float2(t2.x - t3.y, t2.y + t3.x);   // t2 + i*t3
    x0 = make_float2(t0.x + t1.x, t0.y + t1.y);
    x1 = cmul(w1, b1);
    x2 = cmul(w2, make_float2(t0.x - t1.x, t0.y - t1.y));
    x3 = cmul(w3, b3);
}
// radix-8 on 8 elems at q0 + j*L/8; all twiddles derived from w = W_L^{q0}.
__device__ __forceinline__ void r8(float2 x[8], float2 w) {
    const float c = 0.70710678118654752f;
    float2 w2 = csq(w), w3 = cmul(w, w2), w4 = csq(w2);
    r4(x[0], x[2], x[4], x[6], w, w2, w3);
    float2 wE   = make_float2(c * (w.x + w.y),  c * (w.y - w.x));     // w*e^{-i pi/4}
    float2 w2E2 = make_float2(w2.y, -w2.x);                           // w2*(-i)
    float2 w3E3 = make_float2(c * (w3.y - w3.x), -c * (w3.x + w3.y)); // w3*e^{-i3pi/4}
    r4(x[1], x[3], x[5], x[7], wE, w2E2, w3E3);
#pragma unroll
    for (int r = 0; r < 4; ++r) {
        float2 a = x[2 * r], b = x[2 * r + 1];
        x[2 * r]     = make_float2(a.x + b.x, a.y + b.y);
        float2 d     = make_float2(a.x - b.x, a.y - b.y);
        x[2 * r + 1] = cmul(w4, d);
    }
}

// ---------------- Kernel A: 512 threads, in-place 8192-pt complex FFT as
// 3x radix-8 + fused (radix-8 x2 + radix-2 in regs); window+pack fused into
// pass 1 via per-thread base x compile-time rotation. unroll(1) groups.
// Byte-identical to the verified 123.7us round-0 kernel. Rounds 1-2: any
// extra live float2s spill (VGPR wall at 112/128). Round 3: block stagger
// = pure loss (no CU pipe convoy; latency-bound per wave). Round 4: spin-
// barrier fusion of the post path = pure loss. fft is a local optimum. ---
__global__ __launch_bounds__(512, 2) void fft_pow_kernel(
        const float* __restrict__ audio, float* __restrict__ partial, int P) {
    __shared__ float2 buf[8718];   // phi(p) = p + (p>>4) + (p>>9), max 8717
    const int t = threadIdx.x;

    const int phit  = t + (t >> 4);                         // phi(t), t < 512
    const int q2    = t & 127;
    const int base2 = 1090 * (t >> 7) + q2 + (q2 >> 4);     // pass2 base
    const int base3 = 136 * (t >> 4) + ((t >> 4) >> 2) + (t & 15);
    const int base4 = 17 * t + (t >> 5);
    const int tp    = (512 - t) & 511;
    // output position of bin k = t + 512u: PB(t) + off(u) for the
    // radix-[8,8,8,8,2] chain (verified absmax 0 since round 5)
    const int PBt = (t & 3) * 2048 + ((t >> 2) & 1) * 1024 + ((t >> 3) & 3) * 256
                  + ((t >> 5) & 1) * 128 + ((t >> 6) & 3) * 32 + ((t >> 8) & 1) * 16;
    const int PBp = (tp & 3) * 2048 + ((tp >> 2) & 1) * 1024 + ((tp >> 3) & 3) * 256
                  + ((tp >> 5) & 1) * 128 + ((tp >> 6) & 3) * 32 + ((tp >> 8) & 1) * 16;
    const int ubA = PBt + (PBt >> 4) + (PBt >> 9);
    const int ubB = PBp + (PBp >> 4) + (PBp >> 9);

    const float2 ONE = make_float2(1.0f, 0.0f);
    const float2 K8  = make_float2(0.92387953251128674f, -0.38268343236508977f); // e^{-i pi/8}
    const float2 KD  = make_float2(0.99999992646574f, -0.00038349518757f);       // e^{-i pi/8192}
    float2 wU  = make_float2(cospif((float)t * (1.0f / 8192.0f)),
                             -sinpif((float)t * (1.0f / 8192.0f)));  // W_16384^t
    float2 w1  = csq(wU);                                            // W_8192^t
    float2 wodd = cmul(w1, KD);                                      // e^{-i pi(2t+1)/8192}
    float2 w2t = make_float2(cospif((float)q2 * (1.0f / 512.0f)),
                             -sinpif((float)q2 * (1.0f / 512.0f)));  // W_1024^(t&127)
    float2 w3t = make_float2(cospif((float)(t & 15) * (1.0f / 64.0f)),
                             -sinpif((float)(t & 15) * (1.0f / 64.0f))); // W_128^(t&15)
    // untangle twiddle step: W_16384^{512u} = e^{-i pi u/16}, compile-time
    const float K16c[16] = {1.0f, 0.98078528040323044f, 0.92387953251128674f,
        0.83146961230254524f, 0.70710678118654752f, 0.55557023301960222f,
        0.38268343236508977f, 0.19509032201612825f, 0.0f, -0.19509032201612825f,
        -0.38268343236508977f, -0.55557023301960222f, -0.70710678118654752f,
        -0.83146961230254524f, -0.92387953251128674f, -0.98078528040323044f};
    const float K16s[16] = {0.0f, -0.19509032201612825f, -0.38268343236508977f,
        -0.55557023301960222f, -0.70710678118654752f, -0.83146961230254524f,
        -0.92387953251128674f, -0.98078528040323044f, -1.0f, -0.98078528040323044f,
        -0.92387953251128674f, -0.83146961230254524f, -0.70710678118654752f,
        -0.55557023301960222f, -0.38268343236508977f, -0.19509032201612825f};
    // window rotation: cos/sin(pi u/8), u = g + 2j in [0,16)
    const float W16C[16] = {1.0f, 0.92387953251128674f, 0.70710678118654752f,
        0.38268343236508977f, 0.0f, -0.38268343236508977f, -0.70710678118654752f,
        -0.92387953251128674f, -1.0f, -0.92387953251128674f, -0.70710678118654752f,
        -0.38268343236508977f, 0.0f, 0.38268343236508977f, 0.70710678118654752f,
        0.92387953251128674f};
    const float W16S[16] = {0.0f, 0.38268343236508977f, 0.70710678118654752f,
        0.92387953251128674f, 1.0f, 0.92387953251128674f, 0.70710678118654752f,
        0.38268343236508977f, 0.0f, -0.38268343236508977f, -0.70710678118654752f,
        -0.92387953251128674f, -1.0f, -0.92387953251128674f, -0.70710678118654752f,
        -0.38268343236508977f};

    float acc[16];
#pragma unroll
    for (int u = 0; u < 16; ++u) acc[u] = 0.0f;

    for (int f = blockIdx.x; f < T_FRAMES; f += P) {
        __syncthreads();   // previous frame's untangle reads vs pass-1 writes
        // ---- pass 1 (fused window+pack): L=8192, q0 = t + 512g ----
        const bool interior = (f != 0) && (f != T_FRAMES - 1);
        const float2* au2 = (const float2*)audio + 4096 * (f - 1);
        const int baseS = f * 8192 - 8192;
#pragma unroll 1
        for (int g = 0; g < 2; ++g) {
            float2 x[8];
            if (interior) {
#pragma unroll
                for (int j = 0; j < 8; ++j) {
                    int idx = t + 512 * g + 1024 * j;
                    float2 p = au2[idx];
                    const int uix = g + 2 * j;
                    float c0 = 0.5f - 0.5f * (w1.x * W16C[uix] + w1.y * W16S[uix]);
                    float c1 = 0.5f - 0.5f * (wodd.x * W16C[uix] + wodd.y * W16S[uix]);
                    x[j] = make_float2(p.x * c0, p.y * c1);
                }
            } else {
#pragma unroll
                for (int j = 0; j < 8; ++j) {
                    int idx = t + 512 * g + 1024 * j;
                    float a0 = audio[refl_idx(baseS + 2 * idx)];
                    float a1 = audio[refl_idx(baseS + 2 * idx + 1)];
                    const int uix = g + 2 * j;
                    float c0 = 0.5f - 0.5f * (w1.x * W16C[uix] + w1.y * W16S[uix]);
                    float c1 = 0.5f - 0.5f * (wodd.x * W16C[uix] + wodd.y * W16S[uix]);
                    x[j] = make_float2(a0 * c0, a1 * c1);
                }
            }
            float2 w = g ? cmul(w1, K8) : w1;
            r8(x, w);
#pragma unroll
            for (int j = 0; j < 8; ++j) buf[phit + 545 * g + 1090 * j] = x[j];
        }
        __syncthreads();
        // pass 2: L=1024, B = (t>>7)+4g, q0 = t&127, stride 128
#pragma unroll 1
        for (int g = 0; g < 2; ++g) {
            float2 x[8];
            const int bs = base2 + 4360 * g;
#pragma unroll
            for (int j = 0; j < 8; ++j) x[j] = buf[bs + 136 * j + (j >> 2)];
            r8(x, w2t);
#pragma unroll
            for (int j = 0; j < 8; ++j) buf[bs + 136 * j + (j >> 2)] = x[j];
        }
        __syncthreads();
        // pass 3: L=128, B = (t>>4)+32g, q0 = t&15, stride 16
#pragma unroll 1
        for (int g = 0; g < 2; ++g) {
            float2 x[8];
            const int bs = base3 + 4360 * g;
#pragma unroll
            for (int j = 0; j < 8; ++j) x[j] = buf[bs + 17 * j];
            r8(x, w3t);
#pragma unroll
            for (int j = 0; j < 8; ++j) buf[bs + 17 * j] = x[j];
        }
        __syncthreads();
        // pass 4+5 fused: thread t owns logical [16t,16t+16); radix-8 on both
        // parity groups in registers; radix-2 pairs are (a[j], x[j]).
        {
            float2 a[8], x[8];
#pragma unroll
            for (int j = 0; j < 8; ++j) a[j] = buf[base4 + 2 * j];
            r8(a, ONE);
#pragma unroll
            for (int j = 0; j < 8; ++j) x[j] = buf[base4 + 1 + 2 * j];
            r8(x, K8);
#pragma unroll
            for (int j = 0; j < 8; ++j) {
                buf[base4 + 2 * j]     = make_float2(a[j].x + x[j].x, a[j].y + x[j].y);
                buf[base4 + 2 * j + 1] = make_float2(a[j].x - x[j].x, a[j].y - x[j].y);
            }
        }
        __syncthreads();
        // untangle real FFT at digit-reversed positions, power, log
#pragma unroll
        for (int u = 0; u < 16; ++u) {
            const int off = (u & 3) * 4 + ((u >> 2) & 1) * 2 + (u >> 3);
            int u2 = t ? (15 - u) : ((16 - u) & 15);
            int off2 = (u2 & 3) * 4 + ((u2 >> 2) & 1) * 2 + (u2 >> 3);
            float2 A = buf[ubA + off];
            float2 B = buf[ubB + off2];
            float Xer = 0.5f * (A.x + B.x);
            float Xei = 0.5f * (A.y - B.y);
            float Xor = 0.5f * (A.y + B.y);
            float Xoi = -0.5f * (A.x - B.x);
            float2 w = cmul(wU, make_float2(K16c[u], K16s[u]));  // W_16384^{t+512u}
            float Xr = Xer + Xor * w.x - Xoi * w.y;
            float Xi = Xei + Xor * w.y + Xoi * w.x;
            float pw = Xr * Xr + Xi * Xi;
            acc[u] += __logf(fmaf(100.0f, pw, 1.0f));
        }
    }
#pragma unroll
    for (int u = 0; u < 16; ++u)
        partial[(size_t)blockIdx.x * NBINS + t + 512 * u] = acc[u];
}

// ---------------- Kernel B: parallel deterministic reduce -------------------
// Round-5 rewrite: SAME summation order per (bin,g) as the verified kernel
// (a0 = even rows in sequence, a1 = odd rows in sequence, (s0+s1)+(s2+s3))
// -> bit-identical spec. Changes are purely scheduling: (a) 16-deep manual
// load batching so ~16 global loads are in flight per thread (old 2-deep
// chain was latency-bound: 128 strided 4B loads x ~300-900cy); (b) 256
// blocks x 128 threads instead of 128x256 so all 256 CUs issue loads.
__global__ __launch_bounds__(128) void reduce_kernel(
        const float* __restrict__ partial, float* __restrict__ spec, int P) {
    __shared__ float s[4][33];
    const int bin0 = blockIdx.x * 32;
    const int bo = threadIdx.x & 31;
    const int g  = threadIdx.x >> 5;       // 0..3
    const int rows = P >> 2;               // P/4
    float a0 = 0.f, a1 = 0.f;
    int r = 0;
    const float* base = partial + (size_t)g * rows * NBINS + bin0 + bo;
    for (; r + 16 <= rows; r += 16) {
        float l0  = base[(size_t)(r     ) * NBINS];
        float l1  = base[(size_t)(r +  1) * NBINS];
        float l2  = base[(size_t)(r +  2) * NBINS];
        float l3  = base[(size_t)(r +  3) * NBINS];
        float l4  = base[(size_t)(r +  4) * NBINS];
        float l5  = base[(size_t)(r +  5) * NBINS];
        float l6  = base[(size_t)(r +  6) * NBINS];
        float l7  = base[(size_t)(r +  7) * NBINS];
        float l8  = base[(size_t)(r +  8) * NBINS];
        float l9  = base[(size_t)(r +  9) * NBINS];
        float l10 = base[(size_t)(r + 10) * NBINS];
        float l11 = base[(size_t)(r + 11) * NBINS];
        float l12 = base[(size_t)(r + 12) * NBINS];
        float l13 = base[(size_t)(r + 13) * NBINS];
        float l14 = base[(size_t)(r + 14) * NBINS];
        float l15 = base[(size_t)(r + 15) * NBINS];
        // preserve original chain order: a0 gets even rows in sequence,
        // a1 gets odd rows in sequence.
        a0 += l0;  a1 += l1;  a0 += l2;  a1 += l3;
        a0 += l4;  a1 += l5;  a0 += l6;  a1 += l7;
        a0 += l8;  a1 += l9;  a0 += l10; a1 += l11;
        a0 += l12; a1 += l13; a0 += l14; a1 += l15;
    }
    for (; r + 2 <= rows; r += 2) {
        a0 += base[(size_t)r * NBINS];
        a1 += base[(size_t)(r + 1) * NBINS];
    }
    for (; r < rows; ++r) a0 += base[(size_t)r * NBINS];
    s[g][bo] = a0 + a1;
    __syncthreads();
    if (threadIdx.x < 32)
        spec[bin0 + threadIdx.x] = (s[0][threadIdx.x] + s[1][threadIdx.x])
                                 + (s[2][threadIdx.x] + s[3][threadIdx.x]);
}

// ---------------- Kernel C: spline(M local) + eval + smooth + relu ----------
// Each block computes the M-range its own 356 queries need directly from spec
// (64-step Thomas warm-ups are fp32-exact: 0.268^64 < 1e-37). Array sizes are
// for the WORST block (31: full 355-query span at near-max frequency ->
// iHi-iLo = 526 -> ny = 659, dps = 592, Ms = 528); round-13 sized for block 32
// (range 429) and overflowed -> corrupted blocks 30/31 -> absmax 392.
__global__ __launch_bounds__(256) void cent_spline_kernel(
        const float* __restrict__ spec, const float* __restrict__ wsm,
        float* __restrict__ filt) {
    __shared__ float ys[768];
    __shared__ float dps[704];
    __shared__ float Ms[640];
    __shared__ float cs[356];
    __shared__ float wsm_s[101];
    __shared__ float invden_s[64];
    const int tid = threadIdx.x;
    const int j0 = blockIdx.x * 256;
    const float h = 22050.0f / 16384.0f;
    const float hh = h * h;

    if (tid == 0) {
        double v = 0.25;
        invden_s[0] = 0.25f;
        for (int i = 1; i < 64; ++i) { v = 1.0 / (4.0 - v); invden_s[i] = (float)v; }
    }
    for (int r = tid; r < 101; r += 256) wsm_s[r] = wsm[r];

    // ---- per-block bin ranges (uniform across threads) ----
    const int jLo = max(j0 - 50, 0);
    const int jHi = min(j0 + 305, NQ - 1);
    const float xqLo = (float)(440.0 * exp2(((double)jLo * 0.01 - 45.0) * (1.0 / 12.0)));
    const float xqHi = (float)(440.0 * exp2(((double)jHi * 0.01 - 45.0) * (1.0 / 12.0)));
    const int iLo = min(max((int)floorf(xqLo / h), 0), 8190);
    const int iHi = min(max((int)floorf(xqHi / h), 0), 8190);
    const int pLo = max(iLo - 2, 0);           // unknown-index range needed
    const int pHi = min(iHi - 1, MUNK - 1);
    const int bHi = min(pHi + 64, MUNK - 1);   // dp needed up to here (bw warm-up)
    const int yLo = max(pLo - 64, 0);          // y needed from fw warm-up start
    const int yHi = bHi + 3;
    const int ny  = yHi - yLo + 1;

    for (int k = tid; k < ny; k += 256) ys[k] = spec[yLo + k];
    __syncthreads();
    const float cst = invden_s[63];   // 2 - sqrt(3)

    // ---- forward Thomas: dp[pLo..bHi], chunks of 32, 64-step warm-up ----
    {
        const int nch = (bHi - pLo + 32) >> 5;
        if (tid < nch) {
            const int s = pLo + (tid << 5);
            const int e = min(s + 31, bHi);
            const int ws = max(s - 64, 0);
            float dprev = 0.0f;
            for (int i = ws; i <= e; ++i) {
                float d1 = (ys[i + 1 - yLo] - 2.0f * ys[i + 2 - yLo]
                            + ys[i + 3 - yLo]) / hh;
                float r = 6.0f * d1;
                if (i == 0) r -= (ys[0] - 2.0f * ys[1] + ys[2]) / hh;  // yLo==0 here
                // i == MUNK-1 unreachable: bHi <= ~3172 << 8187
                float val = (i == 0) ? r : (r - dprev);
                float dpv = val * ((i < 64) ? invden_s[i] : cst);
                if (i >= s) dps[i - pLo] = dpv;
                dprev = dpv;
            }
        }
    }
    __syncthreads();
    // ---- backward: Ms[2+i-iLo] = x[i], i in [pLo..pHi], 64-step warm-up ----
    {
        const int nch = (pHi - pLo + 32) >> 5;
        if (tid < nch) {
            const int s = pLo + (tid << 5);
            const int e = min(s + 31, pHi);
            const int ws2 = min(e + 64, bHi);
            float xnext = 0.0f;
            for (int i = ws2; i >= s; --i) {
                float cp = (i == MUNK - 1) ? 0.0f : ((i < 64) ? invden_s[i] : cst);
                float xv = dps[i - pLo] - cp * xnext;
                if (i <= e) Ms[2 + i - iLo] = xv;
                xnext = xv;
            }
        }
    }
    __syncthreads();
    // ---- spline eval at this block's queries -> cs ----
    for (int r = tid; r < 356; r += 256) {
        int j = j0 - 50 + r;
        float v = 0.0f;
        if (j >= 0 && j < NQ) {
            double e = ((double)j * 0.01 - 45.0) * (1.0 / 12.0);
            float xq = (float)(440.0 * exp2(e));
            int i = min(max((int)floorf(xq / h), 0), 8190);
            float tt = xq - (float)i * h;
            float uu = h - tt;
            float Mi = Ms[i - iLo], Mi1 = Ms[i + 1 - iLo];
            float yi = ys[i - yLo], yi1 = ys[i + 1 - yLo];
            v = (Mi * uu * uu * uu + Mi1 * tt * tt * tt) / (6.0f * h)
              + (yi - Mi * hh / 6.0f) * uu / h
              + (yi1 - Mi1 * hh / 6.0f) * tt / h;
        }
        cs[r] = v;
    }
    __syncthreads();
    // ---- 101-tap smooth (true convolution) + relu -> filt ----
    int j = j0 + tid;
    if (j < NQ) {
        float s = 0.0f;
        for (int m = 0; m < 101; ++m) s = fmaf(wsm_s[m], cs[tid + 100 - m], s);
        float fv = cs[tid + 50] - s;
        filt[j] = fv > 0.0f ? fv : 0.0f;
    }
}

// ---------------- Kernel D: dilated comb + argmax (fused, 1 block) ----------
__global__ __launch_bounds__(256) void comb_argmax_kernel(
        const float* __restrict__ filt, const float* __restrict__ wdet,
        float* __restrict__ out) {
    __shared__ float fs[NQ];
    __shared__ float wd[84];
    __shared__ float sc[100];
    const int t = threadIdx.x;
    for (int k = t; k < NQ; k += 256) fs[k] = filt[k];
    if (t < 84) wd[t] = wdet[t];
    __syncthreads();
    if (t < 100) {
        float s = 0.0f;
        for (int k = 0; k < 84; ++k) {
            int ix = t - 50 + 100 * k;
            if (ix >= 0) s = fmaf(wd[k], fs[ix], s);
        }
        sc[t] = s;
        out[1 + t] = s;
    }
    __syncthreads();
    if (t < 64) {    // wave argmax, first-max tie-break
        float v = (t < 100) ? sc[t] : -1e30f;
        int i = t;
        int t2 = t + 64;
        float v2 = (t2 < 100) ? sc[t2] : -1e30f;
        if (v2 > v) { v = v2; i = t2; }
#pragma unroll
        for (int off = 32; off; off >>= 1) {
            float ov = __shfl_xor(v, off, 64);
            int   oi = __shfl_xor(i, off, 64);
            if (ov > v || (ov == v && oi < i)) { v = ov; i = oi; }
        }
        if (t == 0) out[0] = (float)(i - 50);
    }
}

extern "C" void kernel_launch(void* const* d_in, const int* in_sizes, int n_in,
                              void* d_out, int out_size, void* d_ws, size_t ws_size,
                              hipStream_t stream) {
    const float* audio = (const float*)d_in[0];
    const float* wsm   = (const float*)d_in[1];
    const float* wdet  = (const float*)d_in[2];
    float* out = (float*)d_out;
    float* ws  = (float*)d_ws;

    long cap = (long)(ws_size / sizeof(float) / NBINS) - 1;
    int P = (int)(cap < 4 ? 4 : (cap > 512 ? 512 : cap));
    P &= ~3;                               // multiple of 4 for the reduce
    float* spec    = ws;
    float* partial = ws + NBINS;           // P rows of 8192
    float* filt    = ws + 2 * NBINS;       // reuses partial rows (dead after reduce)

    hipLaunchKernelGGL(fft_pow_kernel, dim3(P), dim3(512), 0, stream,
                       audio, partial, P);
    hipLaunchKernelGGL(reduce_kernel, dim3(256), dim3(128), 0, stream,
                       partial, spec, P);
    hipLaunchKernelGGL(cent_spline_kernel, dim3(33), dim3(256), 0, stream,
                       spec, wsm, filt);
    hipLaunchKernelGGL(comb_argmax_kernel, dim3(1), dim3(256), 0, stream,
                       filt, wdet, out);
}